// Round 5
// baseline (173.156 us; speedup 1.0000x reference)
//
#include <hip/hip_runtime.h>
#include <math.h>

#define NGRAPH 32
#define CAP 10240        // edge capacity per bucket (mean ~8192 + pad<=7/node, ~12 sigma)
#define EPT 8            // edges per thread in k_part (782 blocks ~ 3/CU)
#define EPB (256 * EPT)  // 2048 edges per partition block
#define BLK 256

// gsum layout: [0..31]=su1, [32..63]=su2, [64..95]=sv3, [96..127]=su3

// ---- block-wide exclusive scan over 256 threads, 2 barriers (shfl-based) ----
__device__ __forceinline__ int block_scan_excl(int v, int tid, int* wsum, int& total) {
    int x = v;
#pragma unroll
    for (int d = 1; d < 64; d <<= 1) {
        int t = __shfl_up(x, d);
        if ((tid & 63) >= d) x += t;
    }
    if ((tid & 63) == 63) wsum[tid >> 6] = x;   // wave inclusive totals
    __syncthreads();
    if (tid == 0) {
        int a = 0;
#pragma unroll
        for (int i = 0; i < 4; i++) { int t = wsum[i]; wsum[i] = a; a += t; }
        wsum[4] = a;
    }
    __syncthreads();
    total = wsum[4];
    return x - v + wsum[tid >> 6];
}

// ---------------- partition edges into fixed-capacity bucket ranges ----------------
// staged word: (bucket << 24) | (src << 8) | (dst & 255)   [src < 65536]
// extra last block computes the weight-chain vectors concurrently (used only by k_mlp).
__global__ __launch_bounds__(256) void k_part_chain(
        const int* __restrict__ src, const int* __restrict__ dst,
        int* __restrict__ gcursor, unsigned int* __restrict__ packed, int E, int nchunk,
        const float* __restrict__ lin_w, const float* __restrict__ lin_b,
        const float* __restrict__ gcn_w, const float* __restrict__ gcn_b,
        float* __restrict__ chainv) {
    __shared__ union {
        struct { unsigned int ldsbuf[EPB]; int hist[256], lofs[256], lcur[256], base[256], wsum[5]; } p;
        struct { float v4[512]; } c;
    } sm;
    int tid = threadIdx.x;

    if ((int)blockIdx.x == nchunk) {
        // ---- weight chain: 4 vectors of 128 through 3 layers (validated R1/R2/R3) ----
        float* v4 = sm.c.v4;
        int j = tid & 127, gg = tid >> 7;   // gg in {0,1}; thread owns vecs {gg, gg+2}
        if (tid < 128) {
            v4[tid]       = lin_w[tid];
            v4[128 + tid] = lin_b[tid];
            v4[256 + tid] = gcn_b[tid];        // b1
            v4[384 + tid] = gcn_b[128 + tid];  // b2
        }
        __syncthreads();
        for (int l = 0; l < 3; l++) {
            const float* W = gcn_w + l * 128 * 128;
            float a0 = 0.f, a1 = 0.f;
            for (int k0 = 0; k0 < 128; k0 += 16) {   // 16 loads in flight per batch
                float wreg[16];
#pragma unroll
                for (int t = 0; t < 16; t++) wreg[t] = W[(k0 + t) * 128 + j];
#pragma unroll
                for (int t = 0; t < 16; t++) {
                    a0 += v4[gg * 128 + k0 + t] * wreg[t];
                    a1 += v4[(gg + 2) * 128 + k0 + t] * wreg[t];
                }
            }
            __syncthreads();
            v4[gg * 128 + j] = a0;             // vec0 (w-chain), vec1 (b-chain): always
            bool upd = (gg == 0) ? (l >= 1) : (l >= 2);  // vec2 from l>=1, vec3 from l>=2
            if (upd) v4[(gg + 2) * 128 + j] = a1;
            __syncthreads();
        }
        chainv[tid]       = v4[tid];
        chainv[256 + tid] = v4[256 + tid];
        return;
    }

    // ---- edge partition: one 2048-edge chunk per block ----
    int e0 = blockIdx.x * EPB;
    sm.p.hist[tid] = 0;
    __syncthreads();
    int d_[EPT], s_[EPT];
#pragma unroll
    for (int c = 0; c < EPT / 4; c++) {
        int e = e0 + c * 1024 + (tid << 2);
        if (e + 3 < E) {
            int4 dv = *(const int4*)&dst[e];
            int4 sv = *(const int4*)&src[e];
            d_[4*c+0] = dv.x; d_[4*c+1] = dv.y; d_[4*c+2] = dv.z; d_[4*c+3] = dv.w;
            s_[4*c+0] = sv.x; s_[4*c+1] = sv.y; s_[4*c+2] = sv.z; s_[4*c+3] = sv.w;
            atomicAdd(&sm.p.hist[dv.x >> 8], 1);
            atomicAdd(&sm.p.hist[dv.y >> 8], 1);
            atomicAdd(&sm.p.hist[dv.z >> 8], 1);
            atomicAdd(&sm.p.hist[dv.w >> 8], 1);
        } else {
#pragma unroll
            for (int k = 0; k < 4; k++) {
                int ee = e + k;
                if (ee < E) {
                    d_[4*c+k] = dst[ee]; s_[4*c+k] = src[ee];
                    atomicAdd(&sm.p.hist[d_[4*c+k] >> 8], 1);
                } else {
                    d_[4*c+k] = -1;
                }
            }
        }
    }
    __syncthreads();
    int v = sm.p.hist[tid];
    int total;
    int excl = block_scan_excl(v, tid, sm.p.wsum, total);
    sm.p.lofs[tid] = excl;
    sm.p.lcur[tid] = excl;
    if (v > 0) sm.p.base[tid] = tid * CAP + atomicAdd(&gcursor[tid], v);
    __syncthreads();
#pragma unroll
    for (int c = 0; c < EPT; c++) {
        int dd = d_[c];
        if (dd >= 0) {
            int bk = dd >> 8;
            int slot = atomicAdd(&sm.p.lcur[bk], 1);
            sm.p.ldsbuf[slot] = ((unsigned int)bk << 24) | ((unsigned int)s_[c] << 8)
                              | (unsigned int)(dd & 255);
        }
    }
    __syncthreads();
    for (int i = tid; i < total; i += BLK) {
        unsigned int w = sm.p.ldsbuf[i];
        int bk = w >> 24;
        packed[sm.p.base[bk] + (i - sm.p.lofs[bk])] = w & 0xFFFFFFu;
    }
}

// ---------------- per-bucket CSR build fully in LDS (pad-to-8, sentinels), coalesced out ----
__global__ __launch_bounds__(256) void k_bucket(
        const unsigned int* __restrict__ packed, const int* __restrict__ gcursor,
        const float* __restrict__ x, const int* __restrict__ batch,
        int* __restrict__ offs, int* __restrict__ deg,
        float* __restrict__ dinv, float2* __restrict__ q0,
        float2* __restrict__ q1, float2* __restrict__ q2,
        unsigned short* __restrict__ csr, float* __restrict__ S, int N) {
    __shared__ unsigned int buf[CAP];                  // 40 KB: single global pass
    __shared__ __align__(16) unsigned short lcsr[CAP]; // 20 KB: CSR staged in LDS
    __shared__ int cnt[256], lcur[256], wsum[5];
    __shared__ float cs[NGRAPH];
    int tid = threadIdx.x;
    int b = blockIdx.x;
    int start = b * CAP;
    int len = gcursor[b];
    cnt[tid] = 0;
    if (tid < NGRAPH) cs[tid] = 0.f;
    __syncthreads();
    for (int e = tid; e < len; e += BLK) {
        unsigned int w = packed[start + e];
        buf[e] = w;
        atomicAdd(&cnt[w & 255], 1);
    }
    __syncthreads();
    int v = cnt[tid];
    int vp = (v + 7) & ~7;          // pad each node's slot to multiple of 8
    int total;
    int excl = block_scan_excl(vp, tid, wsum, total);  // multiple of 8 for every node
    lcur[tid] = excl;
    int node = b * 256 + tid;
    if (node < N) {
        deg[node] = v;
        offs[node] = start + excl;
        float dv = rsqrtf((float)(v + 1));   // +1 self loop
        dinv[node] = dv;
        q0[node] = make_float2(x[node] * dv, dv);
        atomicAdd(&cs[batch[node]], 1.f);
        for (int p = v; p < vp; p++)          // 0..7 sentinel pads -> q[N]=(0,0)
            lcsr[excl + p] = (unsigned short)N;
    }
    if (b == 0 && tid == 0) {
        q0[N] = make_float2(0.f, 0.f);
        q1[N] = make_float2(0.f, 0.f);
        q2[N] = make_float2(0.f, 0.f);
    }
    __syncthreads();
    for (int e = tid; e < len; e += BLK) {
        unsigned int w = buf[e];
        lcsr[atomicAdd(&lcur[w & 255], 1)] = (unsigned short)(w >> 8);
    }
    if (tid < NGRAPH && cs[tid] != 0.f) atomicAdd(&S[tid], cs[tid]);
    __syncthreads();
    // coalesced copy-out: total entries, multiple of 8 (16 B chunks)
    const uint4* ls = (const uint4*)lcsr;
    uint4* gs = (uint4*)&csr[start];        // start*2 bytes, multiple of 16
    for (int i = tid; i < (total >> 3); i += BLK) gs[i] = ls[i];
}

// ---------------- hop1: plain, writes q1 (dv-folded) ----------------
__global__ __launch_bounds__(256) void k_hop1(
        const float2* __restrict__ qin, float2* __restrict__ outv,
        const unsigned short* __restrict__ csr,
        const int* __restrict__ offs, const int* __restrict__ deg,
        const float* __restrict__ dinv, int N) {
    int tid  = threadIdx.x;
    int lane = tid & 3;
    int node = blockIdx.x * 64 + (tid >> 2);
    if (node >= N) return;
    int e = offs[node], ne = deg[node];   // e % 8 == 0; slot padded with sentinels
    float sx = 0.0f, su = 0.0f;
    for (int j = 8 * lane; j < ne; j += 32) {
        ushort4 c0 = *(const ushort4*)&csr[e + j];       // pads -> qin[N] == (0,0)
        ushort4 c1 = *(const ushort4*)&csr[e + j + 4];
        float2 a0 = qin[c0.x], a1 = qin[c0.y], a2 = qin[c0.z], a3 = qin[c0.w];
        float2 b0 = qin[c1.x], b1 = qin[c1.y], b2 = qin[c1.z], b3 = qin[c1.w];
        sx += ((a0.x + a1.x) + (a2.x + a3.x)) + ((b0.x + b1.x) + (b2.x + b3.x));
        su += ((a0.y + a1.y) + (a2.y + a3.y)) + ((b0.y + b1.y) + (b2.y + b3.y));
    }
#pragma unroll
    for (int m = 2; m > 0; m >>= 1) {
        sx += __shfl_xor(sx, m);
        su += __shfl_xor(su, m);
    }
    if (lane == 0) {
        float2 qs = qin[node];
        float dv = dinv[node];
        float px = dv * (sx + qs.x), pu = dv * (su + qs.y);
        outv[node] = make_float2(px * dv, pu * dv);
    }
}

// ---------------- hop2: writes q2, accumulates per-graph su1 = sum q1[n].y/dinv[n] ----
__global__ __launch_bounds__(256) void k_hop2(
        const float2* __restrict__ qin, float2* __restrict__ outv,
        const unsigned short* __restrict__ csr,
        const int* __restrict__ offs, const int* __restrict__ deg,
        const float* __restrict__ dinv, const int* __restrict__ batch,
        float* __restrict__ gsum, int N) {
    __shared__ float aS[NGRAPH];
    int tid  = threadIdx.x;
    int lane = tid & 3;
    int node = blockIdx.x * 64 + (tid >> 2);
    if (tid < NGRAPH) aS[tid] = 0.f;
    __syncthreads();
    if (node < N) {
        int e = offs[node], ne = deg[node];
        float sx = 0.0f, su = 0.0f;
        for (int j = 8 * lane; j < ne; j += 32) {
            ushort4 c0 = *(const ushort4*)&csr[e + j];
            ushort4 c1 = *(const ushort4*)&csr[e + j + 4];
            float2 a0 = qin[c0.x], a1 = qin[c0.y], a2 = qin[c0.z], a3 = qin[c0.w];
            float2 b0 = qin[c1.x], b1 = qin[c1.y], b2 = qin[c1.z], b3 = qin[c1.w];
            sx += ((a0.x + a1.x) + (a2.x + a3.x)) + ((b0.x + b1.x) + (b2.x + b3.x));
            su += ((a0.y + a1.y) + (a2.y + a3.y)) + ((b0.y + b1.y) + (b2.y + b3.y));
        }
#pragma unroll
        for (int m = 2; m > 0; m >>= 1) {
            sx += __shfl_xor(sx, m);
            su += __shfl_xor(su, m);
        }
        if (lane == 0) {
            float2 qs = qin[node];            // q1[node]
            float dv = dinv[node];
            float px = dv * (sx + qs.x), pu = dv * (su + qs.y);
            outv[node] = make_float2(px * dv, pu * dv);
            atomicAdd(&aS[batch[node]], qs.y * (1.0f / dv));   // su1 contribution
        }
    }
    __syncthreads();
    if (tid < NGRAPH) {
        float v = aS[tid];
        if (v != 0.f) atomicAdd(&gsum[tid], v);
    }
}

// ---------------- hop3: no per-node output; accumulates su2, sv3, su3 per graph ----
__global__ __launch_bounds__(256) void k_hop3(
        const float2* __restrict__ qin,
        const unsigned short* __restrict__ csr,
        const int* __restrict__ offs, const int* __restrict__ deg,
        const float* __restrict__ dinv, const int* __restrict__ batch,
        float* __restrict__ gsum, int N) {
    __shared__ float aS[NGRAPH], aV[NGRAPH], aU[NGRAPH];
    int tid  = threadIdx.x;
    int lane = tid & 3;
    int node = blockIdx.x * 64 + (tid >> 2);
    if (tid < NGRAPH) { aS[tid] = 0.f; aV[tid] = 0.f; aU[tid] = 0.f; }
    __syncthreads();
    if (node < N) {
        int e = offs[node], ne = deg[node];
        float sx = 0.0f, su = 0.0f;
        for (int j = 8 * lane; j < ne; j += 32) {
            ushort4 c0 = *(const ushort4*)&csr[e + j];
            ushort4 c1 = *(const ushort4*)&csr[e + j + 4];
            float2 a0 = qin[c0.x], a1 = qin[c0.y], a2 = qin[c0.z], a3 = qin[c0.w];
            float2 b0 = qin[c1.x], b1 = qin[c1.y], b2 = qin[c1.z], b3 = qin[c1.w];
            sx += ((a0.x + a1.x) + (a2.x + a3.x)) + ((b0.x + b1.x) + (b2.x + b3.x));
            su += ((a0.y + a1.y) + (a2.y + a3.y)) + ((b0.y + b1.y) + (b2.y + b3.y));
        }
#pragma unroll
        for (int m = 2; m > 0; m >>= 1) {
            sx += __shfl_xor(sx, m);
            su += __shfl_xor(su, m);
        }
        if (lane == 0) {
            float2 qs = qin[node];            // q2[node]
            float dv = dinv[node];
            float px = dv * (sx + qs.x), pu = dv * (su + qs.y);  // p3, not dv-folded
            int g = batch[node];
            atomicAdd(&aS[g], qs.y * (1.0f / dv));   // su2 contribution
            atomicAdd(&aV[g], px);                   // sv3
            atomicAdd(&aU[g], pu);                   // su3
        }
    }
    __syncthreads();
    if (tid < NGRAPH) {
        float v;
        v = aS[tid]; if (v != 0.f) atomicAdd(&gsum[32 + tid], v);
        v = aV[tid]; if (v != 0.f) atomicAdd(&gsum[64 + tid], v);
        v = aU[tid]; if (v != 0.f) atomicAdd(&gsum[96 + tid], v);
    }
}

// ---------------- readout MLP only (per-graph sums already in gsum) ----------------
__global__ __launch_bounds__(256) void k_mlp(
        const float* __restrict__ S, const float* __restrict__ chainv,
        const float* __restrict__ gsum, const float* __restrict__ gcn_b,
        const float* __restrict__ r1_w, const float* __restrict__ r1_b,
        const float* __restrict__ r2_w, const float* __restrict__ r2_b,
        float* __restrict__ out) {
    __shared__ float pl[128], red[128], r4[256];
    int tid = threadIdx.x;
    int g = blockIdx.x;
    float su1 = gsum[g], su2 = gsum[32 + g], sv3 = gsum[64 + g], su3 = gsum[96 + g];
    float cnt = S[g];
    const float* b3 = gcn_b + 2 * 128;
    if (tid < 128)
        pl[tid] = sv3 * chainv[tid] + su3 * chainv[128 + tid] + su2 * chainv[256 + tid]
                + su1 * chainv[384 + tid] + cnt * b3[tid];
    __syncthreads();
    int j = tid & 127, half = tid >> 7;
    float acc = 0.f;
#pragma unroll 8
    for (int kk = 0; kk < 64; kk++) {
        int k = half * 64 + kk;
        acc += pl[k] * r1_w[k * 128 + j];   // coalesced, L2-resident across 32 blocks
    }
    r4[half * 128 + j] = acc;
    __syncthreads();
    if (tid < 128) {
        float a = r4[tid] + r4[128 + tid] + r1_b[tid];
        red[tid] = tanhf(a) * r2_w[tid];
    }
    __syncthreads();
    for (int sft = 64; sft > 0; sft >>= 1) {
        if (tid < sft) red[tid] += red[tid + sft];
        __syncthreads();
    }
    if (tid == 0) out[g] = red[0] + r2_b[0];
}

extern "C" void kernel_launch(void* const* d_in, const int* in_sizes, int n_in,
                              void* d_out, int out_size, void* d_ws, size_t ws_size,
                              hipStream_t stream) {
    const float* x     = (const float*)d_in[0];
    const int*   eidx  = (const int*)d_in[1];
    const int*   batch = (const int*)d_in[2];
    const float* lin_w = (const float*)d_in[3];
    const float* lin_b = (const float*)d_in[4];
    const float* gcn_w = (const float*)d_in[5];
    const float* gcn_b = (const float*)d_in[6];
    const float* r1_w  = (const float*)d_in[7];
    const float* r1_b  = (const float*)d_in[8];
    const float* r2_w  = (const float*)d_in[9];
    const float* r2_b  = (const float*)d_in[10];

    const int N = in_sizes[0];
    const int E = in_sizes[1] / 2;
    const int* src = eidx;
    const int* dst = eidx + E;
    const int NB = (N + 255) / 256;  // 196 buckets

    // workspace layout: 8B-aligned types first, 4B, then 2B csr last (csr base 16B-aligned)
    char* w = (char*)d_ws;
    float2* q0      = (float2*)w; w += (size_t)(N + 2) * 8;
    float2* q1      = (float2*)w; w += (size_t)(N + 2) * 8;
    float2* q2      = (float2*)w; w += (size_t)(N + 2) * 8;
    unsigned int* packed = (unsigned int*)w; w += (size_t)256 * CAP * 4;
    int*    offs    = (int*)w;    w += (size_t)N * 4;
    int*    deg     = (int*)w;    w += (size_t)N * 4;
    float*  dinv    = (float*)w;  w += (size_t)N * 4;
    int*    gcursor = (int*)w;    w += 256 * 4;   // --- zeroed region start ---
    float*  S       = (float*)w;  w += 64 * 4;
    float*  gsum    = (float*)w;  w += 128 * 4;   // --- zeroed region end (1792 B) ---
    float*  chainv  = (float*)w;  w += 512 * 4;
    unsigned short* csr = (unsigned short*)w; w += (size_t)256 * CAP * 2 + 256;

    // single memset covers gcursor (1024 B) + S (256 B) + gsum (512 B), contiguous
    hipMemsetAsync(gcursor, 0, 256 * 4 + 64 * 4 + 128 * 4, stream);

    const int nchunk = (E + EPB - 1) / EPB;   // 782
    k_part_chain<<<nchunk + 1, 256, 0, stream>>>(src, dst, gcursor, packed, E, nchunk,
                                                 lin_w, lin_b, gcn_w, gcn_b, chainv);
    k_bucket<<<NB, 256, 0, stream>>>(packed, gcursor, x, batch, offs, deg, dinv,
                                     q0, q1, q2, csr, S, N);

    const int hop_blocks = (N + 63) / 64;     // 782
    k_hop1<<<hop_blocks, 256, 0, stream>>>(q0, q1, csr, offs, deg, dinv, N);
    k_hop2<<<hop_blocks, 256, 0, stream>>>(q1, q2, csr, offs, deg, dinv, batch, gsum, N);
    k_hop3<<<hop_blocks, 256, 0, stream>>>(q2, csr, offs, deg, dinv, batch, gsum, N);

    k_mlp<<<NGRAPH, 256, 0, stream>>>(S, chainv, gsum, gcn_b,
                                      r1_w, r1_b, r2_w, r2_b, (float*)d_out);
}

// Round 6
// 165.055 us; speedup vs baseline: 1.0491x; 1.0491x over previous
//
#include <hip/hip_runtime.h>
#include <math.h>

#define NGRAPH 32
#define CAP 10240        // edge capacity per bucket (mean ~8192 + pad<=7/node, ~12 sigma)
#define EPT 8            // edges per thread in k_part (782 blocks ~ 3/CU)
#define EPB (256 * EPT)  // 2048 edges per partition block
#define BLK 256

// ---- block-wide exclusive scan over 256 threads, 2 barriers (shfl-based) ----
__device__ __forceinline__ int block_scan_excl(int v, int tid, int* wsum, int& total) {
    int x = v;
#pragma unroll
    for (int d = 1; d < 64; d <<= 1) {
        int t = __shfl_up(x, d);
        if ((tid & 63) >= d) x += t;
    }
    if ((tid & 63) == 63) wsum[tid >> 6] = x;   // wave inclusive totals
    __syncthreads();
    if (tid == 0) {
        int a = 0;
#pragma unroll
        for (int i = 0; i < 4; i++) { int t = wsum[i]; wsum[i] = a; a += t; }
        wsum[4] = a;
    }
    __syncthreads();
    total = wsum[4];
    return x - v + wsum[tid >> 6];
}

// ---------------- partition edges into fixed-capacity bucket ranges ----------------
// staged word: (bucket << 24) | (src << 8) | (dst & 255)   [src < 65536]
// extra last block computes the weight-chain vectors concurrently (used only by k_mlp).
__global__ __launch_bounds__(256) void k_part_chain(
        const int* __restrict__ src, const int* __restrict__ dst,
        int* __restrict__ gcursor, unsigned int* __restrict__ packed, int E, int nchunk,
        const float* __restrict__ lin_w, const float* __restrict__ lin_b,
        const float* __restrict__ gcn_w, const float* __restrict__ gcn_b,
        float* __restrict__ chainv) {
    __shared__ union {
        struct { unsigned int ldsbuf[EPB]; int hist[256], lofs[256], lcur[256], base[256], wsum[5]; } p;
        struct { float v4[512]; } c;
    } sm;
    int tid = threadIdx.x;

    if ((int)blockIdx.x == nchunk) {
        // ---- weight chain: 4 vectors of 128 through 3 layers (validated R1/R2/R3) ----
        float* v4 = sm.c.v4;
        int j = tid & 127, gg = tid >> 7;   // gg in {0,1}; thread owns vecs {gg, gg+2}
        if (tid < 128) {
            v4[tid]       = lin_w[tid];
            v4[128 + tid] = lin_b[tid];
            v4[256 + tid] = gcn_b[tid];        // b1
            v4[384 + tid] = gcn_b[128 + tid];  // b2
        }
        __syncthreads();
        for (int l = 0; l < 3; l++) {
            const float* W = gcn_w + l * 128 * 128;
            float a0 = 0.f, a1 = 0.f;
            for (int k0 = 0; k0 < 128; k0 += 16) {   // 16 loads in flight per batch
                float wreg[16];
#pragma unroll
                for (int t = 0; t < 16; t++) wreg[t] = W[(k0 + t) * 128 + j];
#pragma unroll
                for (int t = 0; t < 16; t++) {
                    a0 += v4[gg * 128 + k0 + t] * wreg[t];
                    a1 += v4[(gg + 2) * 128 + k0 + t] * wreg[t];
                }
            }
            __syncthreads();
            v4[gg * 128 + j] = a0;             // vec0 (w-chain), vec1 (b-chain): always
            bool upd = (gg == 0) ? (l >= 1) : (l >= 2);  // vec2 from l>=1, vec3 from l>=2
            if (upd) v4[(gg + 2) * 128 + j] = a1;
            __syncthreads();
        }
        chainv[tid]       = v4[tid];
        chainv[256 + tid] = v4[256 + tid];
        return;
    }

    // ---- edge partition: one 2048-edge chunk per block ----
    int e0 = blockIdx.x * EPB;
    sm.p.hist[tid] = 0;
    __syncthreads();
    int d_[EPT], s_[EPT];
#pragma unroll
    for (int c = 0; c < EPT / 4; c++) {
        int e = e0 + c * 1024 + (tid << 2);
        if (e + 3 < E) {
            int4 dv = *(const int4*)&dst[e];
            int4 sv = *(const int4*)&src[e];
            d_[4*c+0] = dv.x; d_[4*c+1] = dv.y; d_[4*c+2] = dv.z; d_[4*c+3] = dv.w;
            s_[4*c+0] = sv.x; s_[4*c+1] = sv.y; s_[4*c+2] = sv.z; s_[4*c+3] = sv.w;
            atomicAdd(&sm.p.hist[dv.x >> 8], 1);
            atomicAdd(&sm.p.hist[dv.y >> 8], 1);
            atomicAdd(&sm.p.hist[dv.z >> 8], 1);
            atomicAdd(&sm.p.hist[dv.w >> 8], 1);
        } else {
#pragma unroll
            for (int k = 0; k < 4; k++) {
                int ee = e + k;
                if (ee < E) {
                    d_[4*c+k] = dst[ee]; s_[4*c+k] = src[ee];
                    atomicAdd(&sm.p.hist[d_[4*c+k] >> 8], 1);
                } else {
                    d_[4*c+k] = -1;
                }
            }
        }
    }
    __syncthreads();
    int v = sm.p.hist[tid];
    int total;
    int excl = block_scan_excl(v, tid, sm.p.wsum, total);
    sm.p.lofs[tid] = excl;
    sm.p.lcur[tid] = excl;
    if (v > 0) sm.p.base[tid] = tid * CAP + atomicAdd(&gcursor[tid], v);
    __syncthreads();
#pragma unroll
    for (int c = 0; c < EPT; c++) {
        int dd = d_[c];
        if (dd >= 0) {
            int bk = dd >> 8;
            int slot = atomicAdd(&sm.p.lcur[bk], 1);
            sm.p.ldsbuf[slot] = ((unsigned int)bk << 24) | ((unsigned int)s_[c] << 8)
                              | (unsigned int)(dd & 255);
        }
    }
    __syncthreads();
    for (int i = tid; i < total; i += BLK) {
        unsigned int w = sm.p.ldsbuf[i];
        int bk = w >> 24;
        packed[sm.p.base[bk] + (i - sm.p.lofs[bk])] = w & 0xFFFFFFu;
    }
}

// ---------------- per-bucket CSR build fully in LDS (pad-to-8, sentinels), coalesced out ----
__global__ __launch_bounds__(256) void k_bucket(
        const unsigned int* __restrict__ packed, const int* __restrict__ gcursor,
        const float* __restrict__ x, const int* __restrict__ batch,
        int* __restrict__ offs, int* __restrict__ deg,
        float* __restrict__ dinv, float2* __restrict__ q0,
        float2* __restrict__ q1, float2* __restrict__ q2,
        unsigned short* __restrict__ csr, float* __restrict__ S, int N) {
    __shared__ unsigned int buf[CAP];                  // 40 KB: single global pass
    __shared__ __align__(16) unsigned short lcsr[CAP]; // 20 KB: CSR staged in LDS
    __shared__ int cnt[256], lcur[256], wsum[5];
    __shared__ float cs[NGRAPH];
    int tid = threadIdx.x;
    int b = blockIdx.x;
    int start = b * CAP;
    int len = gcursor[b];
    cnt[tid] = 0;
    if (tid < NGRAPH) cs[tid] = 0.f;
    __syncthreads();
    for (int e = tid; e < len; e += BLK) {
        unsigned int w = packed[start + e];
        buf[e] = w;
        atomicAdd(&cnt[w & 255], 1);
    }
    __syncthreads();
    int v = cnt[tid];
    int vp = (v + 7) & ~7;          // pad each node's slot to multiple of 8
    int total;
    int excl = block_scan_excl(vp, tid, wsum, total);  // multiple of 8 for every node
    lcur[tid] = excl;
    int node = b * 256 + tid;
    if (node < N) {
        deg[node] = v;
        offs[node] = start + excl;
        float dv = rsqrtf((float)(v + 1));   // +1 self loop
        dinv[node] = dv;
        q0[node] = make_float2(x[node] * dv, dv);
        atomicAdd(&cs[batch[node]], 1.f);
        for (int p = v; p < vp; p++)          // 0..7 sentinel pads -> q[N]=(0,0)
            lcsr[excl + p] = (unsigned short)N;
    }
    if (b == 0 && tid == 0) {
        q0[N] = make_float2(0.f, 0.f);
        q1[N] = make_float2(0.f, 0.f);
        q2[N] = make_float2(0.f, 0.f);
    }
    __syncthreads();
    for (int e = tid; e < len; e += BLK) {
        unsigned int w = buf[e];
        lcsr[atomicAdd(&lcur[w & 255], 1)] = (unsigned short)(w >> 8);
    }
    if (tid < NGRAPH && cs[tid] != 0.f) atomicAdd(&S[tid], cs[tid]);
    __syncthreads();
    // coalesced copy-out: total entries, multiple of 8 (16 B chunks)
    const uint4* ls = (const uint4*)lcsr;
    uint4* gs = (uint4*)&csr[start];        // start*2 bytes, multiple of 16
    for (int i = tid; i < (total >> 3); i += BLK) gs[i] = ls[i];
}

// ---------------- hop1: plain, writes q1 (dv-folded) ----------------
__global__ __launch_bounds__(256) void k_hop1(
        const float2* __restrict__ qin, float2* __restrict__ outv,
        const unsigned short* __restrict__ csr,
        const int* __restrict__ offs, const int* __restrict__ deg,
        const float* __restrict__ dinv, int N) {
    int tid  = threadIdx.x;
    int lane = tid & 3;
    int node = blockIdx.x * 64 + (tid >> 2);
    if (node >= N) return;
    int e = offs[node], ne = deg[node];   // e % 8 == 0; slot padded with sentinels
    float sx = 0.0f, su = 0.0f;
    for (int j = 8 * lane; j < ne; j += 32) {
        ushort4 c0 = *(const ushort4*)&csr[e + j];       // pads -> qin[N] == (0,0)
        ushort4 c1 = *(const ushort4*)&csr[e + j + 4];
        float2 a0 = qin[c0.x], a1 = qin[c0.y], a2 = qin[c0.z], a3 = qin[c0.w];
        float2 b0 = qin[c1.x], b1 = qin[c1.y], b2 = qin[c1.z], b3 = qin[c1.w];
        sx += ((a0.x + a1.x) + (a2.x + a3.x)) + ((b0.x + b1.x) + (b2.x + b3.x));
        su += ((a0.y + a1.y) + (a2.y + a3.y)) + ((b0.y + b1.y) + (b2.y + b3.y));
    }
#pragma unroll
    for (int m = 2; m > 0; m >>= 1) {
        sx += __shfl_xor(sx, m);
        su += __shfl_xor(su, m);
    }
    if (lane == 0) {
        float2 qs = qin[node];
        float dv = dinv[node];
        float px = dv * (sx + qs.x), pu = dv * (su + qs.y);
        outv[node] = make_float2(px * dv, pu * dv);
    }
}

// ---- hop2: writes q2; per-BLOCK per-graph partials of su1 to distinct slots (no atomics) ----
__global__ __launch_bounds__(256) void k_hop2(
        const float2* __restrict__ qin, float2* __restrict__ outv,
        const unsigned short* __restrict__ csr,
        const int* __restrict__ offs, const int* __restrict__ deg,
        const float* __restrict__ dinv, const int* __restrict__ batch,
        float* __restrict__ gp1, int N, int NBLK) {
    __shared__ float aS[NGRAPH];
    int tid  = threadIdx.x;
    int lane = tid & 3;
    int node = blockIdx.x * 64 + (tid >> 2);
    if (tid < NGRAPH) aS[tid] = 0.f;
    __syncthreads();
    if (node < N) {
        int e = offs[node], ne = deg[node];
        float sx = 0.0f, su = 0.0f;
        for (int j = 8 * lane; j < ne; j += 32) {
            ushort4 c0 = *(const ushort4*)&csr[e + j];
            ushort4 c1 = *(const ushort4*)&csr[e + j + 4];
            float2 a0 = qin[c0.x], a1 = qin[c0.y], a2 = qin[c0.z], a3 = qin[c0.w];
            float2 b0 = qin[c1.x], b1 = qin[c1.y], b2 = qin[c1.z], b3 = qin[c1.w];
            sx += ((a0.x + a1.x) + (a2.x + a3.x)) + ((b0.x + b1.x) + (b2.x + b3.x));
            su += ((a0.y + a1.y) + (a2.y + a3.y)) + ((b0.y + b1.y) + (b2.y + b3.y));
        }
#pragma unroll
        for (int m = 2; m > 0; m >>= 1) {
            sx += __shfl_xor(sx, m);
            su += __shfl_xor(su, m);
        }
        if (lane == 0) {
            float2 qs = qin[node];            // q1[node]
            float dv = dinv[node];
            float px = dv * (sx + qs.x), pu = dv * (su + qs.y);
            outv[node] = make_float2(px * dv, pu * dv);
            atomicAdd(&aS[batch[node]], qs.y * (1.0f / dv));   // LDS only
        }
    }
    __syncthreads();
    if (tid < NGRAPH) gp1[tid * NBLK + blockIdx.x] = aS[tid];   // distinct slot per block
}

// ---- hop3: no per-node output; per-block partials of su2, sv3, su3 (no atomics) ----
__global__ __launch_bounds__(256) void k_hop3(
        const float2* __restrict__ qin,
        const unsigned short* __restrict__ csr,
        const int* __restrict__ offs, const int* __restrict__ deg,
        const float* __restrict__ dinv, const int* __restrict__ batch,
        float* __restrict__ gp2, float* __restrict__ gp3, float* __restrict__ gp4,
        int N, int NBLK) {
    __shared__ float aS[NGRAPH], aV[NGRAPH], aU[NGRAPH];
    int tid  = threadIdx.x;
    int lane = tid & 3;
    int node = blockIdx.x * 64 + (tid >> 2);
    if (tid < NGRAPH) { aS[tid] = 0.f; aV[tid] = 0.f; aU[tid] = 0.f; }
    __syncthreads();
    if (node < N) {
        int e = offs[node], ne = deg[node];
        float sx = 0.0f, su = 0.0f;
        for (int j = 8 * lane; j < ne; j += 32) {
            ushort4 c0 = *(const ushort4*)&csr[e + j];
            ushort4 c1 = *(const ushort4*)&csr[e + j + 4];
            float2 a0 = qin[c0.x], a1 = qin[c0.y], a2 = qin[c0.z], a3 = qin[c0.w];
            float2 b0 = qin[c1.x], b1 = qin[c1.y], b2 = qin[c1.z], b3 = qin[c1.w];
            sx += ((a0.x + a1.x) + (a2.x + a3.x)) + ((b0.x + b1.x) + (b2.x + b3.x));
            su += ((a0.y + a1.y) + (a2.y + a3.y)) + ((b0.y + b1.y) + (b2.y + b3.y));
        }
#pragma unroll
        for (int m = 2; m > 0; m >>= 1) {
            sx += __shfl_xor(sx, m);
            su += __shfl_xor(su, m);
        }
        if (lane == 0) {
            float2 qs = qin[node];            // q2[node]
            float dv = dinv[node];
            float px = dv * (sx + qs.x), pu = dv * (su + qs.y);  // p3 values
            int g = batch[node];
            atomicAdd(&aS[g], qs.y * (1.0f / dv));   // su2 (LDS only)
            atomicAdd(&aV[g], px);                   // sv3
            atomicAdd(&aU[g], pu);                   // su3
        }
    }
    __syncthreads();
    if (tid < NGRAPH) {
        int slot = tid * NBLK + blockIdx.x;
        gp2[slot] = aS[tid];
        gp3[slot] = aV[tid];
        gp4[slot] = aU[tid];
    }
}

// ---------------- readout: reduce per-block partials + MLP ----------------
__global__ __launch_bounds__(256) void k_mlp(
        const float* __restrict__ S, const float* __restrict__ chainv,
        const float* __restrict__ gp1, const float* __restrict__ gp2,
        const float* __restrict__ gp3, const float* __restrict__ gp4,
        const float* __restrict__ gcn_b,
        const float* __restrict__ r1_w, const float* __restrict__ r1_b,
        const float* __restrict__ r2_w, const float* __restrict__ r2_b,
        float* __restrict__ out, int NBLK) {
    __shared__ float pl[128], red[128], r4[256];
    int tid = threadIdx.x;
    int g = blockIdx.x;
    float su1 = 0.f, su2 = 0.f, sv3 = 0.f, su3 = 0.f;
    for (int b = tid; b < NBLK; b += BLK) {      // contiguous per-graph rows, coalesced
        su1 += gp1[g * NBLK + b];
        su2 += gp2[g * NBLK + b];
        sv3 += gp3[g * NBLK + b];
        su3 += gp4[g * NBLK + b];
    }
#pragma unroll
    for (int m = 32; m > 0; m >>= 1) {
        su1 += __shfl_xor(su1, m);
        su2 += __shfl_xor(su2, m);
        su3 += __shfl_xor(su3, m);
        sv3 += __shfl_xor(sv3, m);
    }
    int wv = tid >> 6;
    if ((tid & 63) == 0) {
        r4[wv] = su1; r4[4 + wv] = su2; r4[8 + wv] = su3; r4[12 + wv] = sv3;
    }
    __syncthreads();
    su1 = r4[0] + r4[1] + r4[2] + r4[3];
    su2 = r4[4] + r4[5] + r4[6] + r4[7];
    su3 = r4[8] + r4[9] + r4[10] + r4[11];
    sv3 = r4[12] + r4[13] + r4[14] + r4[15];
    float cnt = S[g];
    const float* b3 = gcn_b + 2 * 128;
    if (tid < 128)
        pl[tid] = sv3 * chainv[tid] + su3 * chainv[128 + tid] + su2 * chainv[256 + tid]
                + su1 * chainv[384 + tid] + cnt * b3[tid];
    __syncthreads();
    int j = tid & 127, half = tid >> 7;
    float acc = 0.f;
#pragma unroll 8
    for (int kk = 0; kk < 64; kk++) {
        int k = half * 64 + kk;
        acc += pl[k] * r1_w[k * 128 + j];   // coalesced, L2-resident across 32 blocks
    }
    r4[half * 128 + j] = acc;
    __syncthreads();
    if (tid < 128) {
        float a = r4[tid] + r4[128 + tid] + r1_b[tid];
        red[tid] = tanhf(a) * r2_w[tid];
    }
    __syncthreads();
    for (int sft = 64; sft > 0; sft >>= 1) {
        if (tid < sft) red[tid] += red[tid + sft];
        __syncthreads();
    }
    if (tid == 0) out[g] = red[0] + r2_b[0];
}

extern "C" void kernel_launch(void* const* d_in, const int* in_sizes, int n_in,
                              void* d_out, int out_size, void* d_ws, size_t ws_size,
                              hipStream_t stream) {
    const float* x     = (const float*)d_in[0];
    const int*   eidx  = (const int*)d_in[1];
    const int*   batch = (const int*)d_in[2];
    const float* lin_w = (const float*)d_in[3];
    const float* lin_b = (const float*)d_in[4];
    const float* gcn_w = (const float*)d_in[5];
    const float* gcn_b = (const float*)d_in[6];
    const float* r1_w  = (const float*)d_in[7];
    const float* r1_b  = (const float*)d_in[8];
    const float* r2_w  = (const float*)d_in[9];
    const float* r2_b  = (const float*)d_in[10];

    const int N = in_sizes[0];
    const int E = in_sizes[1] / 2;
    const int* src = eidx;
    const int* dst = eidx + E;
    const int NB = (N + 255) / 256;       // 196 buckets
    const int hop_blocks = (N + 63) / 64; // 782

    // workspace layout: 8B-aligned types first, 4B, then 2B csr last (csr base 16B-aligned)
    char* w = (char*)d_ws;
    float2* q0      = (float2*)w; w += (size_t)(N + 2) * 8;
    float2* q1      = (float2*)w; w += (size_t)(N + 2) * 8;
    float2* q2      = (float2*)w; w += (size_t)(N + 2) * 8;
    unsigned int* packed = (unsigned int*)w; w += (size_t)256 * CAP * 4;
    int*    offs    = (int*)w;    w += (size_t)N * 4;
    int*    deg     = (int*)w;    w += (size_t)N * 4;
    float*  dinv    = (float*)w;  w += (size_t)N * 4;
    float*  gp1     = (float*)w;  w += (size_t)NGRAPH * hop_blocks * 4;  // no pre-zero needed
    float*  gp2     = (float*)w;  w += (size_t)NGRAPH * hop_blocks * 4;
    float*  gp3     = (float*)w;  w += (size_t)NGRAPH * hop_blocks * 4;
    float*  gp4     = (float*)w;  w += (size_t)NGRAPH * hop_blocks * 4;
    int*    gcursor = (int*)w;    w += 256 * 4;   // --- zeroed region start ---
    float*  S       = (float*)w;  w += 64 * 4;    // --- zeroed region end (1280 B) ---
    float*  chainv  = (float*)w;  w += 512 * 4;
    unsigned short* csr = (unsigned short*)w; w += (size_t)256 * CAP * 2 + 256;

    // single memset covers gcursor (1024 B) + S (256 B), contiguous
    hipMemsetAsync(gcursor, 0, 256 * 4 + 64 * 4, stream);

    const int nchunk = (E + EPB - 1) / EPB;   // 782
    k_part_chain<<<nchunk + 1, 256, 0, stream>>>(src, dst, gcursor, packed, E, nchunk,
                                                 lin_w, lin_b, gcn_w, gcn_b, chainv);
    k_bucket<<<NB, 256, 0, stream>>>(packed, gcursor, x, batch, offs, deg, dinv,
                                     q0, q1, q2, csr, S, N);

    k_hop1<<<hop_blocks, 256, 0, stream>>>(q0, q1, csr, offs, deg, dinv, N);
    k_hop2<<<hop_blocks, 256, 0, stream>>>(q1, q2, csr, offs, deg, dinv, batch,
                                           gp1, N, hop_blocks);
    k_hop3<<<hop_blocks, 256, 0, stream>>>(q2, csr, offs, deg, dinv, batch,
                                           gp2, gp3, gp4, N, hop_blocks);

    k_mlp<<<NGRAPH, 256, 0, stream>>>(S, chainv, gp1, gp2, gp3, gp4, gcn_b,
                                      r1_w, r1_b, r2_w, r2_b, (float*)d_out, hop_blocks);
}

// Round 7
// 152.968 us; speedup vs baseline: 1.1320x; 1.0790x over previous
//
#include <hip/hip_runtime.h>
#include <math.h>

#define NGRAPH 32
#define CAP 10240        // edge capacity per bucket (mean ~8192 + pad<=7/node, ~12 sigma)
#define EPT 16           // edges per thread in k_part (392 blocks)
#define EPB (256 * EPT)  // 4096 edges per partition block
#define BLK 256

// ---- block-wide exclusive scan over 256 threads, 2 barriers (shfl-based) ----
__device__ __forceinline__ int block_scan_excl(int v, int tid, int* wsum, int& total) {
    int x = v;
#pragma unroll
    for (int d = 1; d < 64; d <<= 1) {
        int t = __shfl_up(x, d);
        if ((tid & 63) >= d) x += t;
    }
    if ((tid & 63) == 63) wsum[tid >> 6] = x;   // wave inclusive totals
    __syncthreads();
    if (tid == 0) {
        int a = 0;
#pragma unroll
        for (int i = 0; i < 4; i++) { int t = wsum[i]; wsum[i] = a; a += t; }
        wsum[4] = a;
    }
    __syncthreads();
    total = wsum[4];
    return x - v + wsum[tid >> 6];
}

// ---------------- pure edge partition into fixed-capacity bucket ranges ----------------
// staged word: (bucket << 24) | (src << 8) | (dst & 255)   [src < 65536]
__global__ __launch_bounds__(256, 4) void k_part(
        const int* __restrict__ src, const int* __restrict__ dst,
        int* __restrict__ gcursor, unsigned int* __restrict__ packed, int E) {
    __shared__ unsigned int ldsbuf[EPB];   // 16 KB
    __shared__ int hist[256], lofs[256], lcur[256], base[256], wsum[5];
    int tid = threadIdx.x;
    int e0 = blockIdx.x * EPB;
    hist[tid] = 0;
    __syncthreads();
    int d_[EPT], s_[EPT];
#pragma unroll
    for (int c = 0; c < EPT / 4; c++) {
        int e = e0 + c * 1024 + (tid << 2);
        if (e + 3 < E) {
            int4 dv = *(const int4*)&dst[e];
            int4 sv = *(const int4*)&src[e];
            d_[4*c+0] = dv.x; d_[4*c+1] = dv.y; d_[4*c+2] = dv.z; d_[4*c+3] = dv.w;
            s_[4*c+0] = sv.x; s_[4*c+1] = sv.y; s_[4*c+2] = sv.z; s_[4*c+3] = sv.w;
            atomicAdd(&hist[dv.x >> 8], 1);
            atomicAdd(&hist[dv.y >> 8], 1);
            atomicAdd(&hist[dv.z >> 8], 1);
            atomicAdd(&hist[dv.w >> 8], 1);
        } else {
#pragma unroll
            for (int k = 0; k < 4; k++) {
                int ee = e + k;
                if (ee < E) {
                    d_[4*c+k] = dst[ee]; s_[4*c+k] = src[ee];
                    atomicAdd(&hist[d_[4*c+k] >> 8], 1);
                } else {
                    d_[4*c+k] = -1;
                }
            }
        }
    }
    __syncthreads();
    int v = hist[tid];
    int total;
    int excl = block_scan_excl(v, tid, wsum, total);
    lofs[tid] = excl;
    lcur[tid] = excl;
    if (v > 0) base[tid] = tid * CAP + atomicAdd(&gcursor[tid], v);
    __syncthreads();
#pragma unroll
    for (int c = 0; c < EPT; c++) {
        int dd = d_[c];
        if (dd >= 0) {
            int bk = dd >> 8;
            int slot = atomicAdd(&lcur[bk], 1);
            ldsbuf[slot] = ((unsigned int)bk << 24) | ((unsigned int)s_[c] << 8)
                         | (unsigned int)(dd & 255);
        }
    }
    __syncthreads();
    for (int i = tid; i < total; i += BLK) {
        unsigned int w = ldsbuf[i];
        int bk = w >> 24;
        packed[base[bk] + (i - lofs[bk])] = w & 0xFFFFFFu;
    }
}

// ------- per-bucket CSR build in LDS (pad-to-8, sentinels), coalesced out -------
// extra last block (blockIdx == NB) computes the weight-chain vectors instead;
// its ~5 us hide inside the ~20 us bucket phase (k_bucket is LDS-bound, 2 blocks/CU).
__global__ __launch_bounds__(256) void k_bucket_chain(
        const unsigned int* __restrict__ packed, const int* __restrict__ gcursor,
        const float* __restrict__ x, const int* __restrict__ batch,
        int* __restrict__ offs, int* __restrict__ deg,
        float* __restrict__ dinv, float2* __restrict__ q0,
        float2* __restrict__ q1, float2* __restrict__ q2,
        unsigned short* __restrict__ csr, float* __restrict__ S, int N, int NB,
        const float* __restrict__ lin_w, const float* __restrict__ lin_b,
        const float* __restrict__ gcn_w, const float* __restrict__ gcn_b,
        float* __restrict__ chainv) {
    __shared__ union {
        struct {
            unsigned int buf[CAP];                       // 40 KB: single global pass
            __align__(16) unsigned short lcsr[CAP];      // 20 KB: CSR staged in LDS
            int cnt[256], lcur[256], wsum[5];
            float cs[NGRAPH];
        } b;
        struct { float v4[512]; } c;
    } sm;
    int tid = threadIdx.x;
    int b = blockIdx.x;

    if (b == NB) {
        // ---- weight chain: 4 vectors of 128 through 3 layers (validated R1-R6) ----
        float* v4 = sm.c.v4;
        int j = tid & 127, gg = tid >> 7;   // gg in {0,1}; thread owns vecs {gg, gg+2}
        if (tid < 128) {
            v4[tid]       = lin_w[tid];
            v4[128 + tid] = lin_b[tid];
            v4[256 + tid] = gcn_b[tid];        // b1
            v4[384 + tid] = gcn_b[128 + tid];  // b2
        }
        __syncthreads();
        for (int l = 0; l < 3; l++) {
            const float* W = gcn_w + l * 128 * 128;
            float a0 = 0.f, a1 = 0.f;
            for (int k0 = 0; k0 < 128; k0 += 16) {   // 16 loads in flight per batch
                float wreg[16];
#pragma unroll
                for (int t = 0; t < 16; t++) wreg[t] = W[(k0 + t) * 128 + j];
#pragma unroll
                for (int t = 0; t < 16; t++) {
                    a0 += v4[gg * 128 + k0 + t] * wreg[t];
                    a1 += v4[(gg + 2) * 128 + k0 + t] * wreg[t];
                }
            }
            __syncthreads();
            v4[gg * 128 + j] = a0;             // vec0 (w-chain), vec1 (b-chain): always
            bool upd = (gg == 0) ? (l >= 1) : (l >= 2);  // vec2 from l>=1, vec3 from l>=2
            if (upd) v4[(gg + 2) * 128 + j] = a1;
            __syncthreads();
        }
        chainv[tid]       = v4[tid];
        chainv[256 + tid] = v4[256 + tid];
        return;
    }

    int start = b * CAP;
    int len = gcursor[b];
    sm.b.cnt[tid] = 0;
    if (tid < NGRAPH) sm.b.cs[tid] = 0.f;
    __syncthreads();
    for (int e = tid; e < len; e += BLK) {
        unsigned int w = packed[start + e];
        sm.b.buf[e] = w;
        atomicAdd(&sm.b.cnt[w & 255], 1);
    }
    __syncthreads();
    int v = sm.b.cnt[tid];
    int vp = (v + 7) & ~7;          // pad each node's slot to multiple of 8
    int total;
    int excl = block_scan_excl(vp, tid, sm.b.wsum, total);  // multiple of 8 per node
    sm.b.lcur[tid] = excl;
    int node = b * 256 + tid;
    if (node < N) {
        deg[node] = v;
        offs[node] = start + excl;
        float dv = rsqrtf((float)(v + 1));   // +1 self loop
        dinv[node] = dv;
        q0[node] = make_float2(x[node] * dv, dv);
        atomicAdd(&sm.b.cs[batch[node]], 1.f);
        for (int p = v; p < vp; p++)          // 0..7 sentinel pads -> q[N]=(0,0)
            sm.b.lcsr[excl + p] = (unsigned short)N;
    }
    if (b == 0 && tid == 0) {
        q0[N] = make_float2(0.f, 0.f);
        q1[N] = make_float2(0.f, 0.f);
        q2[N] = make_float2(0.f, 0.f);
    }
    __syncthreads();
    for (int e = tid; e < len; e += BLK) {
        unsigned int w = sm.b.buf[e];
        sm.b.lcsr[atomicAdd(&sm.b.lcur[w & 255], 1)] = (unsigned short)(w >> 8);
    }
    if (tid < NGRAPH && sm.b.cs[tid] != 0.f) atomicAdd(&S[tid], sm.b.cs[tid]);
    __syncthreads();
    // coalesced copy-out: total entries, multiple of 8 (16 B chunks)
    const uint4* ls = (const uint4*)sm.b.lcsr;
    uint4* gs = (uint4*)&csr[start];        // start*2 bytes, multiple of 16
    for (int i = tid; i < (total >> 3); i += BLK) gs[i] = ls[i];
}

// ---------------- hop1: plain, writes q1 (dv-folded) ----------------
__global__ __launch_bounds__(256) void k_hop1(
        const float2* __restrict__ qin, float2* __restrict__ outv,
        const unsigned short* __restrict__ csr,
        const int* __restrict__ offs, const int* __restrict__ deg,
        const float* __restrict__ dinv, int N) {
    int tid  = threadIdx.x;
    int lane = tid & 3;
    int node = blockIdx.x * 64 + (tid >> 2);
    if (node >= N) return;
    int e = offs[node], ne = deg[node];   // e % 8 == 0; slot padded with sentinels
    float sx = 0.0f, su = 0.0f;
    for (int j = 8 * lane; j < ne; j += 32) {
        ushort4 c0 = *(const ushort4*)&csr[e + j];       // pads -> qin[N] == (0,0)
        ushort4 c1 = *(const ushort4*)&csr[e + j + 4];
        float2 a0 = qin[c0.x], a1 = qin[c0.y], a2 = qin[c0.z], a3 = qin[c0.w];
        float2 b0 = qin[c1.x], b1 = qin[c1.y], b2 = qin[c1.z], b3 = qin[c1.w];
        sx += ((a0.x + a1.x) + (a2.x + a3.x)) + ((b0.x + b1.x) + (b2.x + b3.x));
        su += ((a0.y + a1.y) + (a2.y + a3.y)) + ((b0.y + b1.y) + (b2.y + b3.y));
    }
#pragma unroll
    for (int m = 2; m > 0; m >>= 1) {
        sx += __shfl_xor(sx, m);
        su += __shfl_xor(su, m);
    }
    if (lane == 0) {
        float2 qs = qin[node];
        float dv = dinv[node];
        float px = dv * (sx + qs.x), pu = dv * (su + qs.y);
        outv[node] = make_float2(px * dv, pu * dv);
    }
}

// ---- hop2: writes q2; per-BLOCK per-graph partials of su1 to distinct slots (no atomics) ----
__global__ __launch_bounds__(256) void k_hop2(
        const float2* __restrict__ qin, float2* __restrict__ outv,
        const unsigned short* __restrict__ csr,
        const int* __restrict__ offs, const int* __restrict__ deg,
        const float* __restrict__ dinv, const int* __restrict__ batch,
        float* __restrict__ gp1, int N, int NBLK) {
    __shared__ float aS[NGRAPH];
    int tid  = threadIdx.x;
    int lane = tid & 3;
    int node = blockIdx.x * 64 + (tid >> 2);
    if (tid < NGRAPH) aS[tid] = 0.f;
    __syncthreads();
    if (node < N) {
        int e = offs[node], ne = deg[node];
        float sx = 0.0f, su = 0.0f;
        for (int j = 8 * lane; j < ne; j += 32) {
            ushort4 c0 = *(const ushort4*)&csr[e + j];
            ushort4 c1 = *(const ushort4*)&csr[e + j + 4];
            float2 a0 = qin[c0.x], a1 = qin[c0.y], a2 = qin[c0.z], a3 = qin[c0.w];
            float2 b0 = qin[c1.x], b1 = qin[c1.y], b2 = qin[c1.z], b3 = qin[c1.w];
            sx += ((a0.x + a1.x) + (a2.x + a3.x)) + ((b0.x + b1.x) + (b2.x + b3.x));
            su += ((a0.y + a1.y) + (a2.y + a3.y)) + ((b0.y + b1.y) + (b2.y + b3.y));
        }
#pragma unroll
        for (int m = 2; m > 0; m >>= 1) {
            sx += __shfl_xor(sx, m);
            su += __shfl_xor(su, m);
        }
        if (lane == 0) {
            float2 qs = qin[node];            // q1[node]
            float dv = dinv[node];
            float px = dv * (sx + qs.x), pu = dv * (su + qs.y);
            outv[node] = make_float2(px * dv, pu * dv);
            atomicAdd(&aS[batch[node]], qs.y * (1.0f / dv));   // LDS only
        }
    }
    __syncthreads();
    if (tid < NGRAPH) gp1[tid * NBLK + blockIdx.x] = aS[tid];   // distinct slot per block
}

// ---- hop3: no per-node output; per-block partials of su2, sv3, su3 (no atomics) ----
__global__ __launch_bounds__(256) void k_hop3(
        const float2* __restrict__ qin,
        const unsigned short* __restrict__ csr,
        const int* __restrict__ offs, const int* __restrict__ deg,
        const float* __restrict__ dinv, const int* __restrict__ batch,
        float* __restrict__ gp2, float* __restrict__ gp3, float* __restrict__ gp4,
        int N, int NBLK) {
    __shared__ float aS[NGRAPH], aV[NGRAPH], aU[NGRAPH];
    int tid  = threadIdx.x;
    int lane = tid & 3;
    int node = blockIdx.x * 64 + (tid >> 2);
    if (tid < NGRAPH) { aS[tid] = 0.f; aV[tid] = 0.f; aU[tid] = 0.f; }
    __syncthreads();
    if (node < N) {
        int e = offs[node], ne = deg[node];
        float sx = 0.0f, su = 0.0f;
        for (int j = 8 * lane; j < ne; j += 32) {
            ushort4 c0 = *(const ushort4*)&csr[e + j];
            ushort4 c1 = *(const ushort4*)&csr[e + j + 4];
            float2 a0 = qin[c0.x], a1 = qin[c0.y], a2 = qin[c0.z], a3 = qin[c0.w];
            float2 b0 = qin[c1.x], b1 = qin[c1.y], b2 = qin[c1.z], b3 = qin[c1.w];
            sx += ((a0.x + a1.x) + (a2.x + a3.x)) + ((b0.x + b1.x) + (b2.x + b3.x));
            su += ((a0.y + a1.y) + (a2.y + a3.y)) + ((b0.y + b1.y) + (b2.y + b3.y));
        }
#pragma unroll
        for (int m = 2; m > 0; m >>= 1) {
            sx += __shfl_xor(sx, m);
            su += __shfl_xor(su, m);
        }
        if (lane == 0) {
            float2 qs = qin[node];            // q2[node]
            float dv = dinv[node];
            float px = dv * (sx + qs.x), pu = dv * (su + qs.y);  // p3 values
            int g = batch[node];
            atomicAdd(&aS[g], qs.y * (1.0f / dv));   // su2 (LDS only)
            atomicAdd(&aV[g], px);                   // sv3
            atomicAdd(&aU[g], pu);                   // su3
        }
    }
    __syncthreads();
    if (tid < NGRAPH) {
        int slot = tid * NBLK + blockIdx.x;
        gp2[slot] = aS[tid];
        gp3[slot] = aV[tid];
        gp4[slot] = aU[tid];
    }
}

// ---------------- readout: reduce per-block partials + MLP ----------------
__global__ __launch_bounds__(256) void k_mlp(
        const float* __restrict__ S, const float* __restrict__ chainv,
        const float* __restrict__ gp1, const float* __restrict__ gp2,
        const float* __restrict__ gp3, const float* __restrict__ gp4,
        const float* __restrict__ gcn_b,
        const float* __restrict__ r1_w, const float* __restrict__ r1_b,
        const float* __restrict__ r2_w, const float* __restrict__ r2_b,
        float* __restrict__ out, int NBLK) {
    __shared__ float pl[128], red[128], r4[256];
    int tid = threadIdx.x;
    int g = blockIdx.x;
    float su1 = 0.f, su2 = 0.f, sv3 = 0.f, su3 = 0.f;
    for (int b = tid; b < NBLK; b += BLK) {      // contiguous per-graph rows, coalesced
        su1 += gp1[g * NBLK + b];
        su2 += gp2[g * NBLK + b];
        sv3 += gp3[g * NBLK + b];
        su3 += gp4[g * NBLK + b];
    }
#pragma unroll
    for (int m = 32; m > 0; m >>= 1) {
        su1 += __shfl_xor(su1, m);
        su2 += __shfl_xor(su2, m);
        su3 += __shfl_xor(su3, m);
        sv3 += __shfl_xor(sv3, m);
    }
    int wv = tid >> 6;
    if ((tid & 63) == 0) {
        r4[wv] = su1; r4[4 + wv] = su2; r4[8 + wv] = su3; r4[12 + wv] = sv3;
    }
    __syncthreads();
    su1 = r4[0] + r4[1] + r4[2] + r4[3];
    su2 = r4[4] + r4[5] + r4[6] + r4[7];
    su3 = r4[8] + r4[9] + r4[10] + r4[11];
    sv3 = r4[12] + r4[13] + r4[14] + r4[15];
    float cnt = S[g];
    const float* b3 = gcn_b + 2 * 128;
    if (tid < 128)
        pl[tid] = sv3 * chainv[tid] + su3 * chainv[128 + tid] + su2 * chainv[256 + tid]
                + su1 * chainv[384 + tid] + cnt * b3[tid];
    __syncthreads();
    int j = tid & 127, half = tid >> 7;
    float acc = 0.f;
#pragma unroll 8
    for (int kk = 0; kk < 64; kk++) {
        int k = half * 64 + kk;
        acc += pl[k] * r1_w[k * 128 + j];   // coalesced, L2-resident across 32 blocks
    }
    r4[half * 128 + j] = acc;
    __syncthreads();
    if (tid < 128) {
        float a = r4[tid] + r4[128 + tid] + r1_b[tid];
        red[tid] = tanhf(a) * r2_w[tid];
    }
    __syncthreads();
    for (int sft = 64; sft > 0; sft >>= 1) {
        if (tid < sft) red[tid] += red[tid + sft];
        __syncthreads();
    }
    if (tid == 0) out[g] = red[0] + r2_b[0];
}

extern "C" void kernel_launch(void* const* d_in, const int* in_sizes, int n_in,
                              void* d_out, int out_size, void* d_ws, size_t ws_size,
                              hipStream_t stream) {
    const float* x     = (const float*)d_in[0];
    const int*   eidx  = (const int*)d_in[1];
    const int*   batch = (const int*)d_in[2];
    const float* lin_w = (const float*)d_in[3];
    const float* lin_b = (const float*)d_in[4];
    const float* gcn_w = (const float*)d_in[5];
    const float* gcn_b = (const float*)d_in[6];
    const float* r1_w  = (const float*)d_in[7];
    const float* r1_b  = (const float*)d_in[8];
    const float* r2_w  = (const float*)d_in[9];
    const float* r2_b  = (const float*)d_in[10];

    const int N = in_sizes[0];
    const int E = in_sizes[1] / 2;
    const int* src = eidx;
    const int* dst = eidx + E;
    const int NB = (N + 255) / 256;       // 196 buckets
    const int hop_blocks = (N + 63) / 64; // 782

    // workspace layout: 8B-aligned types first, 4B, then 2B csr last (csr base 16B-aligned)
    char* w = (char*)d_ws;
    float2* q0      = (float2*)w; w += (size_t)(N + 2) * 8;
    float2* q1      = (float2*)w; w += (size_t)(N + 2) * 8;
    float2* q2      = (float2*)w; w += (size_t)(N + 2) * 8;
    unsigned int* packed = (unsigned int*)w; w += (size_t)256 * CAP * 4;
    int*    offs    = (int*)w;    w += (size_t)N * 4;
    int*    deg     = (int*)w;    w += (size_t)N * 4;
    float*  dinv    = (float*)w;  w += (size_t)N * 4;
    float*  gp1     = (float*)w;  w += (size_t)NGRAPH * hop_blocks * 4;  // no pre-zero needed
    float*  gp2     = (float*)w;  w += (size_t)NGRAPH * hop_blocks * 4;
    float*  gp3     = (float*)w;  w += (size_t)NGRAPH * hop_blocks * 4;
    float*  gp4     = (float*)w;  w += (size_t)NGRAPH * hop_blocks * 4;
    int*    gcursor = (int*)w;    w += 256 * 4;   // --- zeroed region start ---
    float*  S       = (float*)w;  w += 64 * 4;    // --- zeroed region end (1280 B) ---
    float*  chainv  = (float*)w;  w += 512 * 4;
    unsigned short* csr = (unsigned short*)w; w += (size_t)256 * CAP * 2 + 256;

    // single memset covers gcursor (1024 B) + S (256 B), contiguous
    hipMemsetAsync(gcursor, 0, 256 * 4 + 64 * 4, stream);

    const int nchunk = (E + EPB - 1) / EPB;   // 391
    k_part<<<nchunk, 256, 0, stream>>>(src, dst, gcursor, packed, E);
    k_bucket_chain<<<NB + 1, 256, 0, stream>>>(packed, gcursor, x, batch, offs, deg,
                                               dinv, q0, q1, q2, csr, S, N, NB,
                                               lin_w, lin_b, gcn_w, gcn_b, chainv);

    k_hop1<<<hop_blocks, 256, 0, stream>>>(q0, q1, csr, offs, deg, dinv, N);
    k_hop2<<<hop_blocks, 256, 0, stream>>>(q1, q2, csr, offs, deg, dinv, batch,
                                           gp1, N, hop_blocks);
    k_hop3<<<hop_blocks, 256, 0, stream>>>(q2, csr, offs, deg, dinv, batch,
                                           gp2, gp3, gp4, N, hop_blocks);

    k_mlp<<<NGRAPH, 256, 0, stream>>>(S, chainv, gp1, gp2, gp3, gp4, gcn_b,
                                      r1_w, r1_b, r2_w, r2_b, (float*)d_out, hop_blocks);
}

// Round 8
// 148.486 us; speedup vs baseline: 1.1661x; 1.0302x over previous
//
#include <hip/hip_runtime.h>
#include <math.h>

#define NGRAPH 32
#define CAP 10240        // edge capacity per bucket (mean ~8192 + pad<=3/node, ~12 sigma)
#define EPT 16           // edges per thread in k_part (392 blocks)
#define EPB (256 * EPT)  // 4096 edges per partition block
#define BLK 256

// ---- block-wide exclusive scan over 256 threads, 2 barriers (shfl-based) ----
__device__ __forceinline__ int block_scan_excl(int v, int tid, int* wsum, int& total) {
    int x = v;
#pragma unroll
    for (int d = 1; d < 64; d <<= 1) {
        int t = __shfl_up(x, d);
        if ((tid & 63) >= d) x += t;
    }
    if ((tid & 63) == 63) wsum[tid >> 6] = x;   // wave inclusive totals
    __syncthreads();
    if (tid == 0) {
        int a = 0;
#pragma unroll
        for (int i = 0; i < 4; i++) { int t = wsum[i]; wsum[i] = a; a += t; }
        wsum[4] = a;
    }
    __syncthreads();
    total = wsum[4];
    return x - v + wsum[tid >> 6];
}

// ---------------- pure edge partition into fixed-capacity bucket ranges ----------------
// staged word: (bucket << 24) | (src << 8) | (dst & 255)   [src < 65536]
__global__ __launch_bounds__(256, 4) void k_part(
        const int* __restrict__ src, const int* __restrict__ dst,
        int* __restrict__ gcursor, unsigned int* __restrict__ packed, int E) {
    __shared__ unsigned int ldsbuf[EPB];   // 16 KB
    __shared__ int hist[256], lofs[256], lcur[256], base[256], wsum[5];
    int tid = threadIdx.x;
    int e0 = blockIdx.x * EPB;
    hist[tid] = 0;
    __syncthreads();
    int d_[EPT], s_[EPT];
#pragma unroll
    for (int c = 0; c < EPT / 4; c++) {
        int e = e0 + c * 1024 + (tid << 2);
        if (e + 3 < E) {
            int4 dv = *(const int4*)&dst[e];
            int4 sv = *(const int4*)&src[e];
            d_[4*c+0] = dv.x; d_[4*c+1] = dv.y; d_[4*c+2] = dv.z; d_[4*c+3] = dv.w;
            s_[4*c+0] = sv.x; s_[4*c+1] = sv.y; s_[4*c+2] = sv.z; s_[4*c+3] = sv.w;
            atomicAdd(&hist[dv.x >> 8], 1);
            atomicAdd(&hist[dv.y >> 8], 1);
            atomicAdd(&hist[dv.z >> 8], 1);
            atomicAdd(&hist[dv.w >> 8], 1);
        } else {
#pragma unroll
            for (int k = 0; k < 4; k++) {
                int ee = e + k;
                if (ee < E) {
                    d_[4*c+k] = dst[ee]; s_[4*c+k] = src[ee];
                    atomicAdd(&hist[d_[4*c+k] >> 8], 1);
                } else {
                    d_[4*c+k] = -1;
                }
            }
        }
    }
    __syncthreads();
    int v = hist[tid];
    int total;
    int excl = block_scan_excl(v, tid, wsum, total);
    lofs[tid] = excl;
    lcur[tid] = excl;
    if (v > 0) base[tid] = tid * CAP + atomicAdd(&gcursor[tid], v);
    __syncthreads();
#pragma unroll
    for (int c = 0; c < EPT; c++) {
        int dd = d_[c];
        if (dd >= 0) {
            int bk = dd >> 8;
            int slot = atomicAdd(&lcur[bk], 1);
            ldsbuf[slot] = ((unsigned int)bk << 24) | ((unsigned int)s_[c] << 8)
                         | (unsigned int)(dd & 255);
        }
    }
    __syncthreads();
    for (int i = tid; i < total; i += BLK) {
        unsigned int w = ldsbuf[i];
        int bk = w >> 24;
        packed[base[bk] + (i - lofs[bk])] = w & 0xFFFFFFu;
    }
}

// ------- per-bucket CSR build in LDS (pad-to-4, sentinels), coalesced out -------
// writes meta[node] = {offs, deg}; dinv is recomputed in hops as rsqrtf(deg+1).
// extra last block (blockIdx == NB) computes the weight-chain vectors instead.
__global__ __launch_bounds__(256) void k_bucket_chain(
        const unsigned int* __restrict__ packed, const int* __restrict__ gcursor,
        const float* __restrict__ x, const int* __restrict__ batch,
        int2* __restrict__ meta, float2* __restrict__ q0,
        float2* __restrict__ q1, float2* __restrict__ q2,
        unsigned short* __restrict__ csr, float* __restrict__ S, int N, int NB,
        const float* __restrict__ lin_w, const float* __restrict__ lin_b,
        const float* __restrict__ gcn_w, const float* __restrict__ gcn_b,
        float* __restrict__ chainv) {
    __shared__ union {
        struct {
            unsigned int buf[CAP];                       // 40 KB: single global pass
            __align__(16) unsigned short lcsr[CAP];      // 20 KB: CSR staged in LDS
            int cnt[256], lcur[256], wsum[5];
            float cs[NGRAPH];
        } b;
        struct { float v4[512]; } c;
    } sm;
    int tid = threadIdx.x;
    int b = blockIdx.x;

    if (b == NB) {
        // ---- weight chain: 4 vectors of 128 through 3 layers (validated R1-R7) ----
        float* v4 = sm.c.v4;
        int j = tid & 127, gg = tid >> 7;   // gg in {0,1}; thread owns vecs {gg, gg+2}
        if (tid < 128) {
            v4[tid]       = lin_w[tid];
            v4[128 + tid] = lin_b[tid];
            v4[256 + tid] = gcn_b[tid];        // b1
            v4[384 + tid] = gcn_b[128 + tid];  // b2
        }
        __syncthreads();
        for (int l = 0; l < 3; l++) {
            const float* W = gcn_w + l * 128 * 128;
            float a0 = 0.f, a1 = 0.f;
            for (int k0 = 0; k0 < 128; k0 += 16) {   // 16 loads in flight per batch
                float wreg[16];
#pragma unroll
                for (int t = 0; t < 16; t++) wreg[t] = W[(k0 + t) * 128 + j];
#pragma unroll
                for (int t = 0; t < 16; t++) {
                    a0 += v4[gg * 128 + k0 + t] * wreg[t];
                    a1 += v4[(gg + 2) * 128 + k0 + t] * wreg[t];
                }
            }
            __syncthreads();
            v4[gg * 128 + j] = a0;             // vec0 (w-chain), vec1 (b-chain): always
            bool upd = (gg == 0) ? (l >= 1) : (l >= 2);  // vec2 from l>=1, vec3 from l>=2
            if (upd) v4[(gg + 2) * 128 + j] = a1;
            __syncthreads();
        }
        chainv[tid]       = v4[tid];
        chainv[256 + tid] = v4[256 + tid];
        return;
    }

    int start = b * CAP;
    int len = gcursor[b];
    sm.b.cnt[tid] = 0;
    if (tid < NGRAPH) sm.b.cs[tid] = 0.f;
    __syncthreads();
    for (int e = tid; e < len; e += BLK) {
        unsigned int w = packed[start + e];
        sm.b.buf[e] = w;
        atomicAdd(&sm.b.cnt[w & 255], 1);
    }
    __syncthreads();
    int v = sm.b.cnt[tid];
    int vp = (v + 3) & ~3;          // pad each node's slot to multiple of 4
    int total;
    int excl = block_scan_excl(vp, tid, sm.b.wsum, total);  // multiple of 4 per node
    sm.b.lcur[tid] = excl;
    int node = b * 256 + tid;
    if (node < N) {
        meta[node] = make_int2(start + excl, v);
        float dv = rsqrtf((float)(v + 1));   // +1 self loop
        q0[node] = make_float2(x[node] * dv, dv);
        atomicAdd(&sm.b.cs[batch[node]], 1.f);
        for (int p = v; p < vp; p++)          // 0..3 sentinel pads -> q[N]=(0,0)
            sm.b.lcsr[excl + p] = (unsigned short)N;
    }
    if (b == 0 && tid == 0) {
        q0[N] = make_float2(0.f, 0.f);
        q1[N] = make_float2(0.f, 0.f);
        q2[N] = make_float2(0.f, 0.f);
    }
    __syncthreads();
    for (int e = tid; e < len; e += BLK) {
        unsigned int w = sm.b.buf[e];
        sm.b.lcsr[atomicAdd(&sm.b.lcur[w & 255], 1)] = (unsigned short)(w >> 8);
    }
    if (tid < NGRAPH && sm.b.cs[tid] != 0.f) atomicAdd(&S[tid], sm.b.cs[tid]);
    __syncthreads();
    // coalesced copy-out: total entries, multiple of 4 (8 B chunks)
    const uint2* ls = (const uint2*)sm.b.lcsr;
    uint2* gs = (uint2*)&csr[start];        // start*2 bytes, multiple of 8
    for (int i = tid; i < (total >> 2); i += BLK) gs[i] = ls[i];
}

// ---------------- hop1: 8 lanes/node, 1 ushort4 + 4 gathers per lane-round ----------------
__global__ __launch_bounds__(256) void k_hop1(
        const float2* __restrict__ qin, float2* __restrict__ outv,
        const unsigned short* __restrict__ csr,
        const int2* __restrict__ meta, int N) {
    int tid  = threadIdx.x;
    int lane = tid & 7;
    int node = blockIdx.x * 32 + (tid >> 3);
    if (node >= N) return;
    int2 md = meta[node];
    int e = md.x, ne = md.y;              // e % 4 == 0; slot padded with sentinels
    float sx = 0.0f, su = 0.0f;
    for (int j = 4 * lane; j < ne; j += 32) {
        ushort4 c = *(const ushort4*)&csr[e + j];        // pads -> qin[N] == (0,0)
        float2 a0 = qin[c.x], a1 = qin[c.y], a2 = qin[c.z], a3 = qin[c.w];
        sx += (a0.x + a1.x) + (a2.x + a3.x);
        su += (a0.y + a1.y) + (a2.y + a3.y);
    }
#pragma unroll
    for (int m = 4; m > 0; m >>= 1) {
        sx += __shfl_xor(sx, m);
        su += __shfl_xor(su, m);
    }
    if (lane == 0) {
        float2 qs = qin[node];
        float dv = rsqrtf((float)(ne + 1));
        float px = dv * (sx + qs.x), pu = dv * (su + qs.y);
        outv[node] = make_float2(px * dv, pu * dv);
    }
}

// ---- hop2: writes q2; per-BLOCK per-graph partials of su1 to distinct slots ----
__global__ __launch_bounds__(256) void k_hop2(
        const float2* __restrict__ qin, float2* __restrict__ outv,
        const unsigned short* __restrict__ csr,
        const int2* __restrict__ meta, const int* __restrict__ batch,
        float* __restrict__ gp1, int N, int NBLK) {
    __shared__ float aS[NGRAPH];
    int tid  = threadIdx.x;
    int lane = tid & 7;
    int node = blockIdx.x * 32 + (tid >> 3);
    if (tid < NGRAPH) aS[tid] = 0.f;
    __syncthreads();
    if (node < N) {
        int2 md = meta[node];
        int e = md.x, ne = md.y;
        float sx = 0.0f, su = 0.0f;
        for (int j = 4 * lane; j < ne; j += 32) {
            ushort4 c = *(const ushort4*)&csr[e + j];
            float2 a0 = qin[c.x], a1 = qin[c.y], a2 = qin[c.z], a3 = qin[c.w];
            sx += (a0.x + a1.x) + (a2.x + a3.x);
            su += (a0.y + a1.y) + (a2.y + a3.y);
        }
#pragma unroll
        for (int m = 4; m > 0; m >>= 1) {
            sx += __shfl_xor(sx, m);
            su += __shfl_xor(su, m);
        }
        if (lane == 0) {
            float2 qs = qin[node];            // q1[node]
            float dv = rsqrtf((float)(ne + 1));
            float px = dv * (sx + qs.x), pu = dv * (su + qs.y);
            outv[node] = make_float2(px * dv, pu * dv);
            atomicAdd(&aS[batch[node]], qs.y * sqrtf((float)(ne + 1)));  // su1 (LDS)
        }
    }
    __syncthreads();
    if (tid < NGRAPH) gp1[tid * NBLK + blockIdx.x] = aS[tid];   // distinct slot per block
}

// ---- hop3: no per-node output; per-block partials of su2, sv3, su3 ----
__global__ __launch_bounds__(256) void k_hop3(
        const float2* __restrict__ qin,
        const unsigned short* __restrict__ csr,
        const int2* __restrict__ meta, const int* __restrict__ batch,
        float* __restrict__ gp2, float* __restrict__ gp3, float* __restrict__ gp4,
        int N, int NBLK) {
    __shared__ float aS[NGRAPH], aV[NGRAPH], aU[NGRAPH];
    int tid  = threadIdx.x;
    int lane = tid & 7;
    int node = blockIdx.x * 32 + (tid >> 3);
    if (tid < NGRAPH) { aS[tid] = 0.f; aV[tid] = 0.f; aU[tid] = 0.f; }
    __syncthreads();
    if (node < N) {
        int2 md = meta[node];
        int e = md.x, ne = md.y;
        float sx = 0.0f, su = 0.0f;
        for (int j = 4 * lane; j < ne; j += 32) {
            ushort4 c = *(const ushort4*)&csr[e + j];
            float2 a0 = qin[c.x], a1 = qin[c.y], a2 = qin[c.z], a3 = qin[c.w];
            sx += (a0.x + a1.x) + (a2.x + a3.x);
            su += (a0.y + a1.y) + (a2.y + a3.y);
        }
#pragma unroll
        for (int m = 4; m > 0; m >>= 1) {
            sx += __shfl_xor(sx, m);
            su += __shfl_xor(su, m);
        }
        if (lane == 0) {
            float2 qs = qin[node];            // q2[node]
            float dv = rsqrtf((float)(ne + 1));
            float px = dv * (sx + qs.x), pu = dv * (su + qs.y);  // p3 values
            int g = batch[node];
            atomicAdd(&aS[g], qs.y * sqrtf((float)(ne + 1)));    // su2 (LDS)
            atomicAdd(&aV[g], px);                               // sv3
            atomicAdd(&aU[g], pu);                               // su3
        }
    }
    __syncthreads();
    if (tid < NGRAPH) {
        int slot = tid * NBLK + blockIdx.x;
        gp2[slot] = aS[tid];
        gp3[slot] = aV[tid];
        gp4[slot] = aU[tid];
    }
}

// ---------------- readout: reduce per-block partials + MLP ----------------
__global__ __launch_bounds__(256) void k_mlp(
        const float* __restrict__ S, const float* __restrict__ chainv,
        const float* __restrict__ gp1, const float* __restrict__ gp2,
        const float* __restrict__ gp3, const float* __restrict__ gp4,
        const float* __restrict__ gcn_b,
        const float* __restrict__ r1_w, const float* __restrict__ r1_b,
        const float* __restrict__ r2_w, const float* __restrict__ r2_b,
        float* __restrict__ out, int NBLK) {
    __shared__ float pl[128], red[128], r4[256];
    int tid = threadIdx.x;
    int g = blockIdx.x;
    float su1 = 0.f, su2 = 0.f, sv3 = 0.f, su3 = 0.f;
    for (int b = tid; b < NBLK; b += BLK) {      // contiguous per-graph rows, coalesced
        su1 += gp1[g * NBLK + b];
        su2 += gp2[g * NBLK + b];
        sv3 += gp3[g * NBLK + b];
        su3 += gp4[g * NBLK + b];
    }
#pragma unroll
    for (int m = 32; m > 0; m >>= 1) {
        su1 += __shfl_xor(su1, m);
        su2 += __shfl_xor(su2, m);
        su3 += __shfl_xor(su3, m);
        sv3 += __shfl_xor(sv3, m);
    }
    int wv = tid >> 6;
    if ((tid & 63) == 0) {
        r4[wv] = su1; r4[4 + wv] = su2; r4[8 + wv] = su3; r4[12 + wv] = sv3;
    }
    __syncthreads();
    su1 = r4[0] + r4[1] + r4[2] + r4[3];
    su2 = r4[4] + r4[5] + r4[6] + r4[7];
    su3 = r4[8] + r4[9] + r4[10] + r4[11];
    sv3 = r4[12] + r4[13] + r4[14] + r4[15];
    float cnt = S[g];
    const float* b3 = gcn_b + 2 * 128;
    if (tid < 128)
        pl[tid] = sv3 * chainv[tid] + su3 * chainv[128 + tid] + su2 * chainv[256 + tid]
                + su1 * chainv[384 + tid] + cnt * b3[tid];
    __syncthreads();
    int j = tid & 127, half = tid >> 7;
    float acc = 0.f;
#pragma unroll 8
    for (int kk = 0; kk < 64; kk++) {
        int k = half * 64 + kk;
        acc += pl[k] * r1_w[k * 128 + j];   // coalesced, L2-resident across 32 blocks
    }
    r4[half * 128 + j] = acc;
    __syncthreads();
    if (tid < 128) {
        float a = r4[tid] + r4[128 + tid] + r1_b[tid];
        red[tid] = tanhf(a) * r2_w[tid];
    }
    __syncthreads();
    for (int sft = 64; sft > 0; sft >>= 1) {
        if (tid < sft) red[tid] += red[tid + sft];
        __syncthreads();
    }
    if (tid == 0) out[g] = red[0] + r2_b[0];
}

extern "C" void kernel_launch(void* const* d_in, const int* in_sizes, int n_in,
                              void* d_out, int out_size, void* d_ws, size_t ws_size,
                              hipStream_t stream) {
    const float* x     = (const float*)d_in[0];
    const int*   eidx  = (const int*)d_in[1];
    const int*   batch = (const int*)d_in[2];
    const float* lin_w = (const float*)d_in[3];
    const float* lin_b = (const float*)d_in[4];
    const float* gcn_w = (const float*)d_in[5];
    const float* gcn_b = (const float*)d_in[6];
    const float* r1_w  = (const float*)d_in[7];
    const float* r1_b  = (const float*)d_in[8];
    const float* r2_w  = (const float*)d_in[9];
    const float* r2_b  = (const float*)d_in[10];

    const int N = in_sizes[0];
    const int E = in_sizes[1] / 2;
    const int* src = eidx;
    const int* dst = eidx + E;
    const int NB = (N + 255) / 256;       // 196 buckets
    const int hop_blocks = (N + 31) / 32; // 1563

    // workspace layout: 8B-aligned types first, 4B, then 2B csr last (csr base 16B-aligned)
    char* w = (char*)d_ws;
    float2* q0      = (float2*)w; w += (size_t)(N + 2) * 8;
    float2* q1      = (float2*)w; w += (size_t)(N + 2) * 8;
    float2* q2      = (float2*)w; w += (size_t)(N + 2) * 8;
    int2*   meta    = (int2*)w;   w += (size_t)N * 8;
    unsigned int* packed = (unsigned int*)w; w += (size_t)256 * CAP * 4;
    float*  gp1     = (float*)w;  w += (size_t)NGRAPH * hop_blocks * 4;  // no pre-zero needed
    float*  gp2     = (float*)w;  w += (size_t)NGRAPH * hop_blocks * 4;
    float*  gp3     = (float*)w;  w += (size_t)NGRAPH * hop_blocks * 4;
    float*  gp4     = (float*)w;  w += (size_t)NGRAPH * hop_blocks * 4;
    int*    gcursor = (int*)w;    w += 256 * 4;   // --- zeroed region start ---
    float*  S       = (float*)w;  w += 64 * 4;    // --- zeroed region end (1280 B) ---
    float*  chainv  = (float*)w;  w += 512 * 4;
    unsigned short* csr = (unsigned short*)w; w += (size_t)256 * CAP * 2 + 256;

    // single memset covers gcursor (1024 B) + S (256 B), contiguous
    hipMemsetAsync(gcursor, 0, 256 * 4 + 64 * 4, stream);

    const int nchunk = (E + EPB - 1) / EPB;   // 391
    k_part<<<nchunk, 256, 0, stream>>>(src, dst, gcursor, packed, E);
    k_bucket_chain<<<NB + 1, 256, 0, stream>>>(packed, gcursor, x, batch, meta,
                                               q0, q1, q2, csr, S, N, NB,
                                               lin_w, lin_b, gcn_w, gcn_b, chainv);

    k_hop1<<<hop_blocks, 256, 0, stream>>>(q0, q1, csr, meta, N);
    k_hop2<<<hop_blocks, 256, 0, stream>>>(q1, q2, csr, meta, batch, gp1, N, hop_blocks);
    k_hop3<<<hop_blocks, 256, 0, stream>>>(q2, csr, meta, batch, gp2, gp3, gp4,
                                           N, hop_blocks);

    k_mlp<<<NGRAPH, 256, 0, stream>>>(S, chainv, gp1, gp2, gp3, gp4, gcn_b,
                                      r1_w, r1_b, r2_w, r2_b, (float*)d_out, hop_blocks);
}